// Round 3
// baseline (71113.318 us; speedup 1.0000x reference)
//
#include <hip/hip_runtime.h>

#define T_STEPS 32768
#define HID 1024
#define NWG 64           // workgroups (16 rows each)
#define RPG 16
#define PRE_BYTES ((size_t)T_STEPS * HID * 2)   // 64 MB bf16 pre-activations
#define HP_BYTES  (2 * HID * 8)                 // 2 parities x 1024 x u64

typedef float vf4 __attribute__((ext_vector_type(4)));
typedef unsigned uv4 __attribute__((ext_vector_type(4)));
typedef unsigned uv2 __attribute__((ext_vector_type(2)));
typedef unsigned long long u64;

// ---------------- bf16 helpers ----------------
__device__ __forceinline__ unsigned short f2bf(float f) {
    unsigned u = __float_as_uint(f);
    u = (u + 0x7fffu + ((u >> 16) & 1u)) >> 16;
    return (unsigned short)u;
}
__device__ __forceinline__ float bf2f(unsigned short s) {
    return __uint_as_float(((unsigned)s) << 16);
}

// ---------------- Kernel 1: pre[t][j] = x[t,:] . W_x[j,:] + b (unchanged, proven) ----
#define BM 64
#define BN 64
#define BK 16
#define LDST 68

__global__ void __launch_bounds__(256) pre_gemm(
    const float* __restrict__ x, const float* __restrict__ Wi,
    const float* __restrict__ b, unsigned short* __restrict__ pre)
{
    __shared__ float As[BK * LDST];
    __shared__ float Bs[BK * LDST];
    const int tid = threadIdx.x;
    const int t0 = blockIdx.x * BM;
    const int j0 = blockIdx.y * BN;
    const int row = tid >> 2;
    const int kq  = tid & 3;
    const int tx  = tid & 15;
    const int ty  = tid >> 4;

    float c[4][4];
#pragma unroll
    for (int i = 0; i < 4; ++i)
#pragma unroll
        for (int j = 0; j < 4; ++j) c[i][j] = 0.f;

    for (int k0 = 0; k0 < 1024; k0 += BK) {
        float4 a4 = *(const float4*)&x[(size_t)(t0 + row) * 1024 + k0 + 4 * kq];
        float4 b4 = *(const float4*)&Wi[(size_t)(j0 + row) * 2048 + k0 + 4 * kq];
        __syncthreads();
        As[(4 * kq + 0) * LDST + row] = a4.x;
        As[(4 * kq + 1) * LDST + row] = a4.y;
        As[(4 * kq + 2) * LDST + row] = a4.z;
        As[(4 * kq + 3) * LDST + row] = a4.w;
        Bs[(4 * kq + 0) * LDST + row] = b4.x;
        Bs[(4 * kq + 1) * LDST + row] = b4.y;
        Bs[(4 * kq + 2) * LDST + row] = b4.z;
        Bs[(4 * kq + 3) * LDST + row] = b4.w;
        __syncthreads();
#pragma unroll
        for (int kk = 0; kk < BK; ++kk) {
            float4 av = *(const float4*)&As[kk * LDST + 4 * ty];
            float4 bv = *(const float4*)&Bs[kk * LDST + 4 * tx];
            c[0][0] = fmaf(av.x, bv.x, c[0][0]); c[0][1] = fmaf(av.x, bv.y, c[0][1]);
            c[0][2] = fmaf(av.x, bv.z, c[0][2]); c[0][3] = fmaf(av.x, bv.w, c[0][3]);
            c[1][0] = fmaf(av.y, bv.x, c[1][0]); c[1][1] = fmaf(av.y, bv.y, c[1][1]);
            c[1][2] = fmaf(av.y, bv.z, c[1][2]); c[1][3] = fmaf(av.y, bv.w, c[1][3]);
            c[2][0] = fmaf(av.z, bv.x, c[2][0]); c[2][1] = fmaf(av.z, bv.y, c[2][1]);
            c[2][2] = fmaf(av.z, bv.z, c[2][2]); c[2][3] = fmaf(av.z, bv.w, c[2][3]);
            c[3][0] = fmaf(av.w, bv.x, c[3][0]); c[3][1] = fmaf(av.w, bv.y, c[3][1]);
            c[3][2] = fmaf(av.w, bv.z, c[3][2]); c[3][3] = fmaf(av.w, bv.w, c[3][3]);
        }
    }

    float4 bias = *(const float4*)&b[j0 + 4 * tx];
#pragma unroll
    for (int i = 0; i < 4; ++i) {
        int r = t0 + 4 * ty + i;
        ushort4 u;
        u.x = f2bf(c[i][0] + bias.x);
        u.y = f2bf(c[i][1] + bias.y);
        u.z = f2bf(c[i][2] + bias.z);
        u.w = f2bf(c[i][3] + bias.w);
        *(ushort4*)&pre[(size_t)r * 1024 + j0 + 4 * tx] = u;
    }
}

// ---------------- agent-scope (sc1) comm primitives — R1-proven coherence ----------
__device__ __forceinline__ void st8_sc1(u64* p, u64 v) {
    asm volatile("global_store_dwordx2 %0, %1, off sc1" :: "v"(p), "v"(v) : "memory");
}
__device__ __forceinline__ vf4 ldg4_pin(const float* p) {
    vf4 r;
    asm volatile("global_load_dwordx4 %0, %1, off\n\ts_waitcnt vmcnt(0)"
                 : "=v"(r) : "v"(p) : "memory");
    return r;
}
__device__ __forceinline__ void issue32(uv4& a, uv4& b, const u64* p) {
    asm volatile("global_load_dwordx4 %0, %2, off sc1\n\t"
                 "global_load_dwordx4 %1, %2, off offset:16 sc1"
                 : "=v"(a), "=v"(b) : "v"(p));
}
__device__ __forceinline__ void wait2(uv4& a, uv4& b) {
    asm volatile("s_waitcnt vmcnt(2)" : "+v"(a), "+v"(b));
}
__device__ __forceinline__ bool hit4(uv4 a, uv4 b, unsigned tg) {
    return (a.y == tg) & (a.w == tg) & (b.y == tg) & (b.w == tg);
}
__device__ __forceinline__ u64 pack_hv(float v, unsigned t) {
    return ((u64)t << 32) | (u64)__float_as_uint(v);
}
__device__ __forceinline__ float fast_tanh(float x) {
    float a = fabsf(x);
    float e = __expf(a + a);
    float r = 1.f - 2.f * __builtin_amdgcn_rcpf(e + 1.f);
    return copysignf(r, x);
}

// 2-slot pipelined poll of 4 contiguous tagged u64 entries. Tags are
// monotone (old -> tg, stable once tg), so stale/garbage register samples
// can never false-positive: a sampled tag==tg implies true tag==tg and the
// accompanying value dwords (same 16B load) are the final ones.
__device__ __forceinline__ vf4 poll4(const u64* pp, unsigned tg, int& budget) {
    uv4 a0, b0, a1, b1, ra, rb;
    issue32(a0, b0, pp);
    for (;;) {
        issue32(a1, b1, pp);
        wait2(a0, b0);
        if (hit4(a0, b0, tg) || --budget < 0) { ra = a0; rb = b0; break; }
        issue32(a0, b0, pp);
        wait2(a1, b1);
        if (hit4(a1, b1, tg) || --budget < 0) { ra = a1; rb = b1; break; }
    }
    // drain before the slot registers can be reused by the compiler
    asm volatile("s_waitcnt vmcnt(0)"
                 : "+v"(a0), "+v"(b0), "+v"(a1), "+v"(b1));
    return (vf4){__uint_as_float(ra.x), __uint_as_float(ra.z),
                 __uint_as_float(rb.x), __uint_as_float(rb.z)};
}

// ---------------- Kernel 2: serial recurrence (single instance, sc1) ----------------
__global__ void __launch_bounds__(256, 2) rnn_rec(
    const unsigned short* __restrict__ pre,
    const float* __restrict__ Wi,     // W_h = Wi[:, 1024:2048]
    const float* __restrict__ Wo,
    const float* __restrict__ bo,
    float* __restrict__ out,
    u64* hp)                          // [2][1024] u64, zeroed (tag0|h0=0)
{
    const int tid = threadIdx.x;
    const int l   = tid & 63;
    const int w   = tid >> 6;                 // wave 0..3
    const int grp = l >> 4;                   // row group within wave
    const int li  = l & 15;                   // lane within group
    const int rows0 = blockIdx.x * RPG;
    const int myrow = rows0 + 4 * w + grp;
    const int e0 = tid * 4;

    __shared__ __align__(16) float hl[2][HID];
    __shared__ __align__(16) unsigned short stage[2][64][RPG];

    // ---- W_h fragment pinned in VGPRs: row myrow, k = li*4 + 64*j + 0..3 ----
    vf4 wv[16];
    {
        const float* wp = Wi + (size_t)myrow * 2048 + 1024 + li * 4;
#pragma unroll
        for (int j = 0; j < 16; ++j) wv[j] = ldg4_pin(wp + 64 * j);
    }

    // ---- stage pre chunk 0 (steps 1..64) ----
    {
        const int i = tid >> 2, c = (tid & 3) * 4;
        *(ushort4*)&stage[0][i][c] = *(const ushort4*)&pre[(size_t)i * HID + rows0 + c];
    }
    __syncthreads();

    int budget = 4000000;                     // hang-proof watchdog
    uv2 refv = (uv2){0, 0};                   // in-flight pre refill (8B)

    for (int t = 1; t <= T_STEPS; ++t) {
        const int par = (t - 1) & 1;
        const int cb  = (t - 1) >> 6;
        const int ph  = (t - 1) & 63;

        // ---- poll own 4 entries of h_{t-1} ----
        vf4 hv = poll4(hp + (size_t)par * HID + e0, (unsigned)(t - 1), budget);
        *(vf4*)&hl[par][e0] = hv;

        // refill write: data issued at ph==32 has long since landed
        if (ph == 40 && cb + 1 < T_STEPS / 64) {
            asm volatile("s_waitcnt vmcnt(0)" : "+v"(refv));
            const int i = tid >> 2, c = (tid & 3) * 4;
            *(uv2*)&stage[(cb + 1) & 1][i][c] = refv;
        }
        __syncthreads();

        float prevv = bf2f(stage[cb & 1][ph][4 * w + grp]);

        // refill issue: next 64-step chunk of pre (latency amortized off-path)
        if (ph == 32 && cb + 1 < T_STEPS / 64) {
            const int i = tid >> 2, c = (tid & 3) * 4;
            const unsigned short* q = &pre[(size_t)((cb + 1) * 64 + i) * HID + rows0 + c];
            asm volatile("global_load_dwordx2 %0, %1, off" : "=v"(refv) : "v"(q));
        }

        // ---- dot(W_h[myrow], h_{t-1}) : 16 lanes x 64 k ----
        const float* hb = hl[par];
        float acc0 = 0.f, acc1 = 0.f;
#pragma unroll
        for (int j = 0; j < 16; j += 2) {
            vf4 a = *(const vf4*)&hb[li * 4 + 64 * j];
            vf4 b = *(const vf4*)&hb[li * 4 + 64 * (j + 1)];
            acc0 = fmaf(wv[j].x, a.x, acc0);
            acc0 = fmaf(wv[j].y, a.y, acc0);
            acc0 = fmaf(wv[j].z, a.z, acc0);
            acc0 = fmaf(wv[j].w, a.w, acc0);
            acc1 = fmaf(wv[j + 1].x, b.x, acc1);
            acc1 = fmaf(wv[j + 1].y, b.y, acc1);
            acc1 = fmaf(wv[j + 1].z, b.z, acc1);
            acc1 = fmaf(wv[j + 1].w, b.w, acc1);
        }
        float s = acc0 + acc1;
        s += __shfl_xor(s, 1);
        s += __shfl_xor(s, 2);
        s += __shfl_xor(s, 4);
        s += __shfl_xor(s, 8);

        if (li == 0) {
            float h = fast_tanh(prevv + s);
            st8_sc1(&hp[(size_t)(t & 1) * HID + myrow], pack_hv(h, (unsigned)t));
        }
    }

    // ---- final projection: out = h_T . W_h2o^T + b_h2o ----
    {
        vf4 hv = poll4(hp + (size_t)((T_STEPS & 1) * HID) + e0,
                       (unsigned)T_STEPS, budget);
        *(vf4*)&hl[0][e0] = hv;
        __syncthreads();

        const float* hb = hl[0];
        const float* wo = Wo + (size_t)myrow * 1024;
        float acc0 = 0.f, acc1 = 0.f;
#pragma unroll
        for (int j = 0; j < 16; j += 2) {
            vf4 a  = *(const vf4*)&hb[li * 4 + 64 * j];
            vf4 b  = *(const vf4*)&hb[li * 4 + 64 * (j + 1)];
            vf4 wa = *(const vf4*)&wo[li * 4 + 64 * j];
            vf4 wb = *(const vf4*)&wo[li * 4 + 64 * (j + 1)];
            acc0 = fmaf(wa.x, a.x, acc0);
            acc0 = fmaf(wa.y, a.y, acc0);
            acc0 = fmaf(wa.z, a.z, acc0);
            acc0 = fmaf(wa.w, a.w, acc0);
            acc1 = fmaf(wb.x, b.x, acc1);
            acc1 = fmaf(wb.y, b.y, acc1);
            acc1 = fmaf(wb.z, b.z, acc1);
            acc1 = fmaf(wb.w, b.w, acc1);
        }
        float s = acc0 + acc1;
        s += __shfl_xor(s, 1);
        s += __shfl_xor(s, 2);
        s += __shfl_xor(s, 4);
        s += __shfl_xor(s, 8);
        if (li == 0) out[myrow] = s + bo[myrow];
    }
    asm volatile("s_waitcnt vmcnt(0)" ::: "memory");
}

extern "C" void kernel_launch(void* const* d_in, const int* in_sizes, int n_in,
                              void* d_out, int out_size, void* d_ws, size_t ws_size,
                              hipStream_t stream) {
    const float* x     = (const float*)d_in[0];   // (1, 32768, 1024)
    const float* W_i2h = (const float*)d_in[1];   // (1024, 2048)
    const float* b_i2h = (const float*)d_in[2];   // (1024,)
    const float* W_h2o = (const float*)d_in[3];   // (1024, 1024)
    const float* b_h2o = (const float*)d_in[4];   // (1024,)
    float* out = (float*)d_out;

    char* base = (char*)d_ws;
    unsigned short* pre = (unsigned short*)base;
    u64* hp = (u64*)(base + PRE_BYTES);

    hipMemsetAsync(hp, 0, HP_BYTES, stream);      // h_0 = 0 with tag 0
    pre_gemm<<<dim3(T_STEPS / BM, HID / BN), 256, 0, stream>>>(x, W_i2h, b_i2h, pre);
    rnn_rec<<<NWG, 256, 0, stream>>>(pre, W_i2h, W_h2o, b_h2o, out, hp);
}

// Round 4
// 64714.270 us; speedup vs baseline: 1.0989x; 1.0989x over previous
//
#include <hip/hip_runtime.h>

#define T_STEPS 32768
#define HID 1024
#define NWG 64                                  // 64 WGs x 16 rows
#define PRE_BYTES ((size_t)T_STEPS * HID * 2)   // 64 MB bf16 pre-activations
#define HP_BYTES  (2 * HID * 8)                 // 2 parities x 1024 x u64

typedef float vf4 __attribute__((ext_vector_type(4)));
typedef unsigned long long u64;

// ---------------- bf16 helpers ----------------
__device__ __forceinline__ unsigned short f2bf(float f) {
    unsigned u = __float_as_uint(f);
    u = (u + 0x7fffu + ((u >> 16) & 1u)) >> 16;
    return (unsigned short)u;
}
__device__ __forceinline__ float bf2f(unsigned short s) {
    return __uint_as_float(((unsigned)s) << 16);
}

// ---------------- Kernel 1: pre[t][j] = x[t,:] . W_x[j,:] + b (unchanged, proven) ----
#define BM 64
#define BN 64
#define BK 16
#define LDST 68

__global__ void __launch_bounds__(256) pre_gemm(
    const float* __restrict__ x, const float* __restrict__ Wi,
    const float* __restrict__ b, unsigned short* __restrict__ pre)
{
    __shared__ float As[BK * LDST];
    __shared__ float Bs[BK * LDST];
    const int tid = threadIdx.x;
    const int t0 = blockIdx.x * BM;
    const int j0 = blockIdx.y * BN;
    const int row = tid >> 2;
    const int kq  = tid & 3;
    const int tx  = tid & 15;
    const int ty  = tid >> 4;

    float c[4][4];
#pragma unroll
    for (int i = 0; i < 4; ++i)
#pragma unroll
        for (int j = 0; j < 4; ++j) c[i][j] = 0.f;

    for (int k0 = 0; k0 < 1024; k0 += BK) {
        float4 a4 = *(const float4*)&x[(size_t)(t0 + row) * 1024 + k0 + 4 * kq];
        float4 b4 = *(const float4*)&Wi[(size_t)(j0 + row) * 2048 + k0 + 4 * kq];
        __syncthreads();
        As[(4 * kq + 0) * LDST + row] = a4.x;
        As[(4 * kq + 1) * LDST + row] = a4.y;
        As[(4 * kq + 2) * LDST + row] = a4.z;
        As[(4 * kq + 3) * LDST + row] = a4.w;
        Bs[(4 * kq + 0) * LDST + row] = b4.x;
        Bs[(4 * kq + 1) * LDST + row] = b4.y;
        Bs[(4 * kq + 2) * LDST + row] = b4.z;
        Bs[(4 * kq + 3) * LDST + row] = b4.w;
        __syncthreads();
#pragma unroll
        for (int kk = 0; kk < BK; ++kk) {
            float4 av = *(const float4*)&As[kk * LDST + 4 * ty];
            float4 bv = *(const float4*)&Bs[kk * LDST + 4 * tx];
            c[0][0] = fmaf(av.x, bv.x, c[0][0]); c[0][1] = fmaf(av.x, bv.y, c[0][1]);
            c[0][2] = fmaf(av.x, bv.z, c[0][2]); c[0][3] = fmaf(av.x, bv.w, c[0][3]);
            c[1][0] = fmaf(av.y, bv.x, c[1][0]); c[1][1] = fmaf(av.y, bv.y, c[1][1]);
            c[1][2] = fmaf(av.y, bv.z, c[1][2]); c[1][3] = fmaf(av.y, bv.w, c[1][3]);
            c[2][0] = fmaf(av.z, bv.x, c[2][0]); c[2][1] = fmaf(av.z, bv.y, c[2][1]);
            c[2][2] = fmaf(av.z, bv.z, c[2][2]); c[2][3] = fmaf(av.z, bv.w, c[2][3]);
            c[3][0] = fmaf(av.w, bv.x, c[3][0]); c[3][1] = fmaf(av.w, bv.y, c[3][1]);
            c[3][2] = fmaf(av.w, bv.z, c[3][2]); c[3][3] = fmaf(av.w, bv.w, c[3][3]);
        }
    }

    float4 bias = *(const float4*)&b[j0 + 4 * tx];
#pragma unroll
    for (int i = 0; i < 4; ++i) {
        int r = t0 + 4 * ty + i;
        ushort4 u;
        u.x = f2bf(c[i][0] + bias.x);
        u.y = f2bf(c[i][1] + bias.y);
        u.z = f2bf(c[i][2] + bias.z);
        u.w = f2bf(c[i][3] + bias.w);
        *(ushort4*)&pre[(size_t)r * 1024 + j0 + 4 * tx] = u;
    }
}

// ---------------- helpers for the recurrent kernel ----------------
__device__ __forceinline__ vf4 ldg4_pin(const float* p) {
    vf4 r;
    asm volatile("global_load_dwordx4 %0, %1, off\n\ts_waitcnt vmcnt(0)"
                 : "=v"(r) : "v"(p) : "memory");
    return r;
}
__device__ __forceinline__ u64 pack_hv(float v, unsigned t) {
    return ((u64)t << 32) | (u64)__float_as_uint(v);
}
__device__ __forceinline__ float fast_tanh(float x) {
    float a = fabsf(x);
    float e = __expf(a + a);                    // e^{2|x|}; inf -> r = 1
    float r = 1.f - 2.f * __builtin_amdgcn_rcpf(e + 1.f);
    return copysignf(r, x);
}

// ---------------- Kernel 2: serial recurrence ----------------
// 64 WGs x 1024 threads. Wave w of WG b owns row r = 16b + w.
// Lane l holds W_h[r][16l .. 16l+15] in 4 vf4 registers (16 VGPRs total —
// small enough that the allocator keeps it resident; fixes R1/R3's spill).
// Mailbox: hp[2][1024] tagged (tag<<32|float) words, agent-scope relaxed
// atomics (R1-proven coherent). Each thread polls exactly one entry.
__global__ void __launch_bounds__(1024, 4) rnn_rec(
    const unsigned short* __restrict__ pre,
    const float* __restrict__ Wi,     // W_h = Wi[:, 1024:2048]
    const float* __restrict__ Wo,
    const float* __restrict__ bo,
    float* __restrict__ out,
    u64* hp)                          // [2][1024] u64, zeroed (tag0|h0=0)
{
    const int tid = threadIdx.x;
    const int w   = tid >> 6;                  // wave 0..15
    const int l   = tid & 63;                  // lane
    const int r   = blockIdx.x * 16 + w;       // this wave's row

    __shared__ __align__(16) float hl[2][HID];
    __shared__ int s_abort;
    if (tid == 0) s_abort = 0;

    // ---- W_h fragment: 4 vf4 per lane, contiguous 64B at k = 16*l ----
    vf4 wv0, wv1, wv2, wv3;
    {
        const float* wp = Wi + (size_t)r * 2048 + 1024 + 16 * l;
        wv0 = ldg4_pin(wp + 0);
        wv1 = ldg4_pin(wp + 4);
        wv2 = ldg4_pin(wp + 8);
        wv3 = ldg4_pin(wp + 12);
    }
    __syncthreads();                            // also covers s_abort init

    int budget = 4000000;                       // hang-proof watchdog

    for (int t = 1; t <= T_STEPS; ++t) {
        const int par = (t - 1) & 1;

        // pre-activation (2B): issue before the poll so latency hides under it
        float prev = 0.f;
        if (l == 0) prev = bf2f(pre[(size_t)(t - 1) * HID + r]);

        // ---- poll own single entry of h_{t-1} (simple, R1-style) ----
        {
            const u64* src = hp + (size_t)par * HID + tid;
            const unsigned tg = (unsigned)(t - 1);
            u64 q;
            for (;;) {
                q = __hip_atomic_load(src, __ATOMIC_RELAXED, __HIP_MEMORY_SCOPE_AGENT);
                if ((unsigned)(q >> 32) == tg) break;
                if (--budget < 0) { s_abort = 1; break; }
            }
            hl[par][tid] = __uint_as_float((unsigned)q);
        }
        __syncthreads();
        if (s_abort) return;                    // uniform exit (post-barrier)

        // ---- dot(W_h[r], h_{t-1}) : lane l covers k = 16l .. 16l+15 ----
        const float* hb = &hl[par][16 * l];
        vf4 a0 = *(const vf4*)&hb[0];
        vf4 a1 = *(const vf4*)&hb[4];
        vf4 a2 = *(const vf4*)&hb[8];
        vf4 a3 = *(const vf4*)&hb[12];
        float acc0 = 0.f, acc1 = 0.f;
        acc0 = fmaf(wv0.x, a0.x, acc0); acc0 = fmaf(wv0.y, a0.y, acc0);
        acc0 = fmaf(wv0.z, a0.z, acc0); acc0 = fmaf(wv0.w, a0.w, acc0);
        acc1 = fmaf(wv1.x, a1.x, acc1); acc1 = fmaf(wv1.y, a1.y, acc1);
        acc1 = fmaf(wv1.z, a1.z, acc1); acc1 = fmaf(wv1.w, a1.w, acc1);
        acc0 = fmaf(wv2.x, a2.x, acc0); acc0 = fmaf(wv2.y, a2.y, acc0);
        acc0 = fmaf(wv2.z, a2.z, acc0); acc0 = fmaf(wv2.w, a2.w, acc0);
        acc1 = fmaf(wv3.x, a3.x, acc1); acc1 = fmaf(wv3.y, a3.y, acc1);
        acc1 = fmaf(wv3.z, a3.z, acc1); acc1 = fmaf(wv3.w, a3.w, acc1);
        float s = acc0 + acc1;
        s += __shfl_xor(s, 1);
        s += __shfl_xor(s, 2);
        s += __shfl_xor(s, 4);
        s += __shfl_xor(s, 8);
        s += __shfl_xor(s, 16);
        s += __shfl_xor(s, 32);

        if (l == 0) {
            float h = fast_tanh(prev + s);
            __hip_atomic_store(&hp[(size_t)(t & 1) * HID + r], pack_hv(h, (unsigned)t),
                               __ATOMIC_RELAXED, __HIP_MEMORY_SCOPE_AGENT);
        }
    }

    // ---- final projection: out = h_T . W_h2o^T + b_h2o ----
    {
        const int par = T_STEPS & 1;
        const u64* src = hp + (size_t)par * HID + tid;
        const unsigned tg = (unsigned)T_STEPS;
        u64 q;
        for (;;) {
            q = __hip_atomic_load(src, __ATOMIC_RELAXED, __HIP_MEMORY_SCOPE_AGENT);
            if ((unsigned)(q >> 32) == tg) break;
            if (--budget < 0) { s_abort = 1; break; }
        }
        hl[0][tid] = __uint_as_float((unsigned)q);
        __syncthreads();
        if (s_abort) return;

        const float* hb = &hl[0][16 * l];
        const float* wo = Wo + (size_t)r * 1024 + 16 * l;
        vf4 a0 = *(const vf4*)&hb[0];
        vf4 a1 = *(const vf4*)&hb[4];
        vf4 a2 = *(const vf4*)&hb[8];
        vf4 a3 = *(const vf4*)&hb[12];
        vf4 w0 = *(const vf4*)&wo[0];
        vf4 w1 = *(const vf4*)&wo[4];
        vf4 w2 = *(const vf4*)&wo[8];
        vf4 w3 = *(const vf4*)&wo[12];
        float acc0 = 0.f, acc1 = 0.f;
        acc0 = fmaf(w0.x, a0.x, acc0); acc0 = fmaf(w0.y, a0.y, acc0);
        acc0 = fmaf(w0.z, a0.z, acc0); acc0 = fmaf(w0.w, a0.w, acc0);
        acc1 = fmaf(w1.x, a1.x, acc1); acc1 = fmaf(w1.y, a1.y, acc1);
        acc1 = fmaf(w1.z, a1.z, acc1); acc1 = fmaf(w1.w, a1.w, acc1);
        acc0 = fmaf(w2.x, a2.x, acc0); acc0 = fmaf(w2.y, a2.y, acc0);
        acc0 = fmaf(w2.z, a2.z, acc0); acc0 = fmaf(w2.w, a2.w, acc0);
        acc1 = fmaf(w3.x, a3.x, acc1); acc1 = fmaf(w3.y, a3.y, acc1);
        acc1 = fmaf(w3.z, a3.z, acc1); acc1 = fmaf(w3.w, a3.w, acc1);
        float s = acc0 + acc1;
        s += __shfl_xor(s, 1);
        s += __shfl_xor(s, 2);
        s += __shfl_xor(s, 4);
        s += __shfl_xor(s, 8);
        s += __shfl_xor(s, 16);
        s += __shfl_xor(s, 32);
        if (l == 0) out[r] = s + bo[r];
    }
}

extern "C" void kernel_launch(void* const* d_in, const int* in_sizes, int n_in,
                              void* d_out, int out_size, void* d_ws, size_t ws_size,
                              hipStream_t stream) {
    const float* x     = (const float*)d_in[0];   // (1, 32768, 1024)
    const float* W_i2h = (const float*)d_in[1];   // (1024, 2048)
    const float* b_i2h = (const float*)d_in[2];   // (1024,)
    const float* W_h2o = (const float*)d_in[3];   // (1024, 1024)
    const float* b_h2o = (const float*)d_in[4];   // (1024,)
    float* out = (float*)d_out;

    char* base = (char*)d_ws;
    unsigned short* pre = (unsigned short*)base;
    u64* hp = (u64*)(base + PRE_BYTES);

    hipMemsetAsync(hp, 0, HP_BYTES, stream);      // h_0 = 0 with tag 0
    pre_gemm<<<dim3(T_STEPS / BM, HID / BN), 256, 0, stream>>>(x, W_i2h, b_i2h, pre);
    rnn_rec<<<NWG, 1024, 0, stream>>>(pre, W_i2h, W_h2o, b_h2o, out, hp);
}

// Round 5
// 63741.895 us; speedup vs baseline: 1.1156x; 1.0153x over previous
//
#include <hip/hip_runtime.h>

#define T_STEPS 32768
#define HID 1024
#define NWG 128                                 // 128 WGs x 8 rows
#define RPW 8                                   // rows per WG (1 per wave)
#define MBS 8                                   // mailbox stride (u64) = 64B/row
#define PRE_BYTES ((size_t)T_STEPS * HID * 2)   // 64 MB bf16 pre-activations
#define HP_BYTES  (2 * HID * MBS * 8)           // 2 parities x 1024 rows x 64B

typedef float vf4 __attribute__((ext_vector_type(4)));
typedef unsigned long long u64;

// ---------------- bf16 helpers ----------------
__device__ __forceinline__ unsigned short f2bf(float f) {
    unsigned u = __float_as_uint(f);
    u = (u + 0x7fffu + ((u >> 16) & 1u)) >> 16;
    return (unsigned short)u;
}
__device__ __forceinline__ float bf2f(unsigned short s) {
    return __uint_as_float(((unsigned)s) << 16);
}

// ---------------- Kernel 1: pre[t][j] = x[t,:] . W_x[j,:] + b (unchanged, proven) ----
#define BM 64
#define BN 64
#define BK 16
#define LDST 68

__global__ void __launch_bounds__(256) pre_gemm(
    const float* __restrict__ x, const float* __restrict__ Wi,
    const float* __restrict__ b, unsigned short* __restrict__ pre)
{
    __shared__ float As[BK * LDST];
    __shared__ float Bs[BK * LDST];
    const int tid = threadIdx.x;
    const int t0 = blockIdx.x * BM;
    const int j0 = blockIdx.y * BN;
    const int row = tid >> 2;
    const int kq  = tid & 3;
    const int tx  = tid & 15;
    const int ty  = tid >> 4;

    float c[4][4];
#pragma unroll
    for (int i = 0; i < 4; ++i)
#pragma unroll
        for (int j = 0; j < 4; ++j) c[i][j] = 0.f;

    for (int k0 = 0; k0 < 1024; k0 += BK) {
        float4 a4 = *(const float4*)&x[(size_t)(t0 + row) * 1024 + k0 + 4 * kq];
        float4 b4 = *(const float4*)&Wi[(size_t)(j0 + row) * 2048 + k0 + 4 * kq];
        __syncthreads();
        As[(4 * kq + 0) * LDST + row] = a4.x;
        As[(4 * kq + 1) * LDST + row] = a4.y;
        As[(4 * kq + 2) * LDST + row] = a4.z;
        As[(4 * kq + 3) * LDST + row] = a4.w;
        Bs[(4 * kq + 0) * LDST + row] = b4.x;
        Bs[(4 * kq + 1) * LDST + row] = b4.y;
        Bs[(4 * kq + 2) * LDST + row] = b4.z;
        Bs[(4 * kq + 3) * LDST + row] = b4.w;
        __syncthreads();
#pragma unroll
        for (int kk = 0; kk < BK; ++kk) {
            float4 av = *(const float4*)&As[kk * LDST + 4 * ty];
            float4 bv = *(const float4*)&Bs[kk * LDST + 4 * tx];
            c[0][0] = fmaf(av.x, bv.x, c[0][0]); c[0][1] = fmaf(av.x, bv.y, c[0][1]);
            c[0][2] = fmaf(av.x, bv.z, c[0][2]); c[0][3] = fmaf(av.x, bv.w, c[0][3]);
            c[1][0] = fmaf(av.y, bv.x, c[1][0]); c[1][1] = fmaf(av.y, bv.y, c[1][1]);
            c[1][2] = fmaf(av.y, bv.z, c[1][2]); c[1][3] = fmaf(av.y, bv.w, c[1][3]);
            c[2][0] = fmaf(av.z, bv.x, c[2][0]); c[2][1] = fmaf(av.z, bv.y, c[2][1]);
            c[2][2] = fmaf(av.z, bv.z, c[2][2]); c[2][3] = fmaf(av.z, bv.w, c[2][3]);
            c[3][0] = fmaf(av.w, bv.x, c[3][0]); c[3][1] = fmaf(av.w, bv.y, c[3][1]);
            c[3][2] = fmaf(av.w, bv.z, c[3][2]); c[3][3] = fmaf(av.w, bv.w, c[3][3]);
        }
    }

    float4 bias = *(const float4*)&b[j0 + 4 * tx];
#pragma unroll
    for (int i = 0; i < 4; ++i) {
        int r = t0 + 4 * ty + i;
        ushort4 u;
        u.x = f2bf(c[i][0] + bias.x);
        u.y = f2bf(c[i][1] + bias.y);
        u.z = f2bf(c[i][2] + bias.z);
        u.w = f2bf(c[i][3] + bias.w);
        *(ushort4*)&pre[(size_t)r * 1024 + j0 + 4 * tx] = u;
    }
}

// ---------------- helpers for the recurrent kernel ----------------
__device__ __forceinline__ vf4 ldg4_pin(const float* p) {
    vf4 r;
    asm volatile("global_load_dwordx4 %0, %1, off\n\ts_waitcnt vmcnt(0)"
                 : "=v"(r) : "v"(p) : "memory");
    return r;
}
__device__ __forceinline__ u64 pack_hv(float v, unsigned t) {
    return ((u64)t << 32) | (u64)__float_as_uint(v);
}
__device__ __forceinline__ float fast_tanh(float x) {
    float a = fabsf(x);
    float e = __expf(a + a);                    // e^{2|x|}; inf -> r = 1
    float r = 1.f - 2.f * __builtin_amdgcn_rcpf(e + 1.f);
    return copysignf(r, x);
}

// ---------------- Kernel 2: serial recurrence ----------------
// 128 WGs x 512 threads. Wave w (0..7) of WG b owns row r = 8b + w.
// Lane l holds W_h[r][k], k = 4l + 256j, j=0..3 (4 vf4 = 16 VGPRs; resident).
// Mailbox: hp[2][1024] tagged u64, ONE 64B LINE PER ROW (stride MBS) so no
// two producers share a cache line (kills R4's partial-line writeback storm).
// Each thread polls 2 rows. LDS dot mapping is conflict-free (16B lane stride).
__global__ void __launch_bounds__(512, 2) rnn_rec(
    const unsigned short* __restrict__ pre,
    const float* __restrict__ Wi,     // W_h = Wi[:, 1024:2048]
    const float* __restrict__ Wo,
    const float* __restrict__ bo,
    float* __restrict__ out,
    u64* hp)                          // [2][1024*MBS] u64, zeroed (tag0|h0=0)
{
    const int tid = threadIdx.x;
    const int w   = tid >> 6;                  // wave 0..7
    const int l   = tid & 63;                  // lane
    const int r   = blockIdx.x * RPW + w;      // this wave's row

    __shared__ __align__(16) float hl[2][HID];
    __shared__ int s_abort;
    if (tid == 0) s_abort = 0;

    // ---- W_h fragment: lane l covers k = 4l + 256j ----
    vf4 wv0, wv1, wv2, wv3;
    {
        const float* wp = Wi + (size_t)r * 2048 + 1024 + 4 * l;
        wv0 = ldg4_pin(wp + 0);
        wv1 = ldg4_pin(wp + 256);
        wv2 = ldg4_pin(wp + 512);
        wv3 = ldg4_pin(wp + 768);
    }
    __syncthreads();                            // covers s_abort init

    int budget = 8000000;                       // hang-proof watchdog
    const int e0 = 2 * tid, e1 = 2 * tid + 1;   // rows this thread polls

    for (int t = 1; t <= T_STEPS; ++t) {
        const int par = (t - 1) & 1;

        // pre-activation (2B): issue before the poll so latency hides under it
        float prev = 0.f;
        if (l == 0) prev = bf2f(pre[(size_t)(t - 1) * HID + r]);

        // ---- poll own 2 mailbox lines of h_{t-1} ----
        {
            const u64* s0 = hp + (size_t)par * (HID * MBS) + (size_t)e0 * MBS;
            const u64* s1 = hp + (size_t)par * (HID * MBS) + (size_t)e1 * MBS;
            const unsigned tg = (unsigned)(t - 1);
            u64 q0, q1;
            for (;;) {
                q0 = __hip_atomic_load(s0, __ATOMIC_RELAXED, __HIP_MEMORY_SCOPE_AGENT);
                q1 = __hip_atomic_load(s1, __ATOMIC_RELAXED, __HIP_MEMORY_SCOPE_AGENT);
                if (((unsigned)(q0 >> 32) == tg) & ((unsigned)(q1 >> 32) == tg)) break;
                if (--budget < 0) { s_abort = 1; break; }
            }
            float2 v;
            v.x = __uint_as_float((unsigned)q0);
            v.y = __uint_as_float((unsigned)q1);
            *(float2*)&hl[par][e0] = v;         // b64, 8B lane stride: 2-way = free
        }
        __syncthreads();
        if (s_abort) return;                    // uniform exit (post-barrier)

        // ---- dot(W_h[r], h_{t-1}) : k = 4l + 256j, conflict-free b128 reads ----
        const float* hb = hl[par];
        vf4 a0 = *(const vf4*)&hb[4 * l + 0];
        vf4 a1 = *(const vf4*)&hb[4 * l + 256];
        vf4 a2 = *(const vf4*)&hb[4 * l + 512];
        vf4 a3 = *(const vf4*)&hb[4 * l + 768];
        float acc0 = 0.f, acc1 = 0.f;
        acc0 = fmaf(wv0.x, a0.x, acc0); acc0 = fmaf(wv0.y, a0.y, acc0);
        acc0 = fmaf(wv0.z, a0.z, acc0); acc0 = fmaf(wv0.w, a0.w, acc0);
        acc1 = fmaf(wv1.x, a1.x, acc1); acc1 = fmaf(wv1.y, a1.y, acc1);
        acc1 = fmaf(wv1.z, a1.z, acc1); acc1 = fmaf(wv1.w, a1.w, acc1);
        acc0 = fmaf(wv2.x, a2.x, acc0); acc0 = fmaf(wv2.y, a2.y, acc0);
        acc0 = fmaf(wv2.z, a2.z, acc0); acc0 = fmaf(wv2.w, a2.w, acc0);
        acc1 = fmaf(wv3.x, a3.x, acc1); acc1 = fmaf(wv3.y, a3.y, acc1);
        acc1 = fmaf(wv3.z, a3.z, acc1); acc1 = fmaf(wv3.w, a3.w, acc1);
        float s = acc0 + acc1;
        s += __shfl_xor(s, 1);
        s += __shfl_xor(s, 2);
        s += __shfl_xor(s, 4);
        s += __shfl_xor(s, 8);
        s += __shfl_xor(s, 16);
        s += __shfl_xor(s, 32);

        if (l == 0) {
            float h = fast_tanh(prev + s);
            __hip_atomic_store(&hp[(size_t)(t & 1) * (HID * MBS) + (size_t)r * MBS],
                               pack_hv(h, (unsigned)t),
                               __ATOMIC_RELAXED, __HIP_MEMORY_SCOPE_AGENT);
        }
    }

    // ---- final projection: out = h_T . W_h2o^T + b_h2o ----
    {
        const int par = T_STEPS & 1;
        const u64* s0 = hp + (size_t)par * (HID * MBS) + (size_t)e0 * MBS;
        const u64* s1 = hp + (size_t)par * (HID * MBS) + (size_t)e1 * MBS;
        const unsigned tg = (unsigned)T_STEPS;
        u64 q0, q1;
        for (;;) {
            q0 = __hip_atomic_load(s0, __ATOMIC_RELAXED, __HIP_MEMORY_SCOPE_AGENT);
            q1 = __hip_atomic_load(s1, __ATOMIC_RELAXED, __HIP_MEMORY_SCOPE_AGENT);
            if (((unsigned)(q0 >> 32) == tg) & ((unsigned)(q1 >> 32) == tg)) break;
            if (--budget < 0) { s_abort = 1; break; }
        }
        float2 v;
        v.x = __uint_as_float((unsigned)q0);
        v.y = __uint_as_float((unsigned)q1);
        *(float2*)&hl[0][e0] = v;
        __syncthreads();
        if (s_abort) return;

        const float* hb = hl[0];
        const float* wo = Wo + (size_t)r * 1024 + 4 * l;
        vf4 a0 = *(const vf4*)&hb[4 * l + 0];
        vf4 a1 = *(const vf4*)&hb[4 * l + 256];
        vf4 a2 = *(const vf4*)&hb[4 * l + 512];
        vf4 a3 = *(const vf4*)&hb[4 * l + 768];
        vf4 w0 = *(const vf4*)&wo[0];
        vf4 w1 = *(const vf4*)&wo[256];
        vf4 w2 = *(const vf4*)&wo[512];
        vf4 w3 = *(const vf4*)&wo[768];
        float acc0 = 0.f, acc1 = 0.f;
        acc0 = fmaf(w0.x, a0.x, acc0); acc0 = fmaf(w0.y, a0.y, acc0);
        acc0 = fmaf(w0.z, a0.z, acc0); acc0 = fmaf(w0.w, a0.w, acc0);
        acc1 = fmaf(w1.x, a1.x, acc1); acc1 = fmaf(w1.y, a1.y, acc1);
        acc1 = fmaf(w1.z, a1.z, acc1); acc1 = fmaf(w1.w, a1.w, acc1);
        acc0 = fmaf(w2.x, a2.x, acc0); acc0 = fmaf(w2.y, a2.y, acc0);
        acc0 = fmaf(w2.z, a2.z, acc0); acc0 = fmaf(w2.w, a2.w, acc0);
        acc1 = fmaf(w3.x, a3.x, acc1); acc1 = fmaf(w3.y, a3.y, acc1);
        acc1 = fmaf(w3.z, a3.z, acc1); acc1 = fmaf(w3.w, a3.w, acc1);
        float s = acc0 + acc1;
        s += __shfl_xor(s, 1);
        s += __shfl_xor(s, 2);
        s += __shfl_xor(s, 4);
        s += __shfl_xor(s, 8);
        s += __shfl_xor(s, 16);
        s += __shfl_xor(s, 32);
        if (l == 0) out[r] = s + bo[r];
    }
}

extern "C" void kernel_launch(void* const* d_in, const int* in_sizes, int n_in,
                              void* d_out, int out_size, void* d_ws, size_t ws_size,
                              hipStream_t stream) {
    const float* x     = (const float*)d_in[0];   // (1, 32768, 1024)
    const float* W_i2h = (const float*)d_in[1];   // (1024, 2048)
    const float* b_i2h = (const float*)d_in[2];   // (1024,)
    const float* W_h2o = (const float*)d_in[3];   // (1024, 1024)
    const float* b_h2o = (const float*)d_in[4];   // (1024,)
    float* out = (float*)d_out;

    char* base = (char*)d_ws;
    unsigned short* pre = (unsigned short*)base;
    u64* hp = (u64*)(base + PRE_BYTES);

    hipMemsetAsync(hp, 0, HP_BYTES, stream);      // h_0 = 0 with tag 0
    pre_gemm<<<dim3(T_STEPS / BM, HID / BN), 256, 0, stream>>>(x, W_i2h, b_i2h, pre);
    rnn_rec<<<NWG, 512, 0, stream>>>(pre, W_i2h, W_h2o, b_h2o, out, hp);
}

// Round 6
// 62831.885 us; speedup vs baseline: 1.1318x; 1.0145x over previous
//
#include <hip/hip_runtime.h>

#define T_STEPS 32768
#define HID 1024
#define NWG 128                                 // 128 WGs x 8 rows
#define RPW 8                                   // rows per WG (1 per wave)
#define PRE_BYTES ((size_t)T_STEPS * HID * 2)   // 64 MB bf16 pre-activations
#define HP_BYTES  (2 * HID * 8)                 // 2 parities x 1024 tagged u64 (16 KB)

typedef float vf4 __attribute__((ext_vector_type(4)));
typedef unsigned uv4 __attribute__((ext_vector_type(4)));
typedef unsigned long long u64;

// ---------------- bf16 helpers ----------------
__device__ __forceinline__ unsigned short f2bf(float f) {
    unsigned u = __float_as_uint(f);
    u = (u + 0x7fffu + ((u >> 16) & 1u)) >> 16;
    return (unsigned short)u;
}
__device__ __forceinline__ float bf2f(unsigned short s) {
    return __uint_as_float(((unsigned)s) << 16);
}

// ---------------- Kernel 1: pre[t][j] = x[t,:] . W_x[j,:] + b (unchanged, proven) ----
#define BM 64
#define BN 64
#define BK 16
#define LDST 68

__global__ void __launch_bounds__(256) pre_gemm(
    const float* __restrict__ x, const float* __restrict__ Wi,
    const float* __restrict__ b, unsigned short* __restrict__ pre)
{
    __shared__ float As[BK * LDST];
    __shared__ float Bs[BK * LDST];
    const int tid = threadIdx.x;
    const int t0 = blockIdx.x * BM;
    const int j0 = blockIdx.y * BN;
    const int row = tid >> 2;
    const int kq  = tid & 3;
    const int tx  = tid & 15;
    const int ty  = tid >> 4;

    float c[4][4];
#pragma unroll
    for (int i = 0; i < 4; ++i)
#pragma unroll
        for (int j = 0; j < 4; ++j) c[i][j] = 0.f;

    for (int k0 = 0; k0 < 1024; k0 += BK) {
        float4 a4 = *(const float4*)&x[(size_t)(t0 + row) * 1024 + k0 + 4 * kq];
        float4 b4 = *(const float4*)&Wi[(size_t)(j0 + row) * 2048 + k0 + 4 * kq];
        __syncthreads();
        As[(4 * kq + 0) * LDST + row] = a4.x;
        As[(4 * kq + 1) * LDST + row] = a4.y;
        As[(4 * kq + 2) * LDST + row] = a4.z;
        As[(4 * kq + 3) * LDST + row] = a4.w;
        Bs[(4 * kq + 0) * LDST + row] = b4.x;
        Bs[(4 * kq + 1) * LDST + row] = b4.y;
        Bs[(4 * kq + 2) * LDST + row] = b4.z;
        Bs[(4 * kq + 3) * LDST + row] = b4.w;
        __syncthreads();
#pragma unroll
        for (int kk = 0; kk < BK; ++kk) {
            float4 av = *(const float4*)&As[kk * LDST + 4 * ty];
            float4 bv = *(const float4*)&Bs[kk * LDST + 4 * tx];
            c[0][0] = fmaf(av.x, bv.x, c[0][0]); c[0][1] = fmaf(av.x, bv.y, c[0][1]);
            c[0][2] = fmaf(av.x, bv.z, c[0][2]); c[0][3] = fmaf(av.x, bv.w, c[0][3]);
            c[1][0] = fmaf(av.y, bv.x, c[1][0]); c[1][1] = fmaf(av.y, bv.y, c[1][1]);
            c[1][2] = fmaf(av.y, bv.z, c[1][2]); c[1][3] = fmaf(av.y, bv.w, c[1][3]);
            c[2][0] = fmaf(av.z, bv.x, c[2][0]); c[2][1] = fmaf(av.z, bv.y, c[2][1]);
            c[2][2] = fmaf(av.z, bv.z, c[2][2]); c[2][3] = fmaf(av.z, bv.w, c[2][3]);
            c[3][0] = fmaf(av.w, bv.x, c[3][0]); c[3][1] = fmaf(av.w, bv.y, c[3][1]);
            c[3][2] = fmaf(av.w, bv.z, c[3][2]); c[3][3] = fmaf(av.w, bv.w, c[3][3]);
        }
    }

    float4 bias = *(const float4*)&b[j0 + 4 * tx];
#pragma unroll
    for (int i = 0; i < 4; ++i) {
        int r = t0 + 4 * ty + i;
        ushort4 u;
        u.x = f2bf(c[i][0] + bias.x);
        u.y = f2bf(c[i][1] + bias.y);
        u.z = f2bf(c[i][2] + bias.z);
        u.w = f2bf(c[i][3] + bias.w);
        *(ushort4*)&pre[(size_t)r * 1024 + j0 + 4 * tx] = u;
    }
}

// ---------------- helpers for the recurrent kernel ----------------
__device__ __forceinline__ vf4 ldg4_pin(const float* p) {
    vf4 r;
    asm volatile("global_load_dwordx4 %0, %1, off\n\ts_waitcnt vmcnt(0)"
                 : "=v"(r) : "v"(p) : "memory");
    return r;
}
__device__ __forceinline__ u64 pack_hv(float v, unsigned t) {
    return ((u64)t << 32) | (u64)__float_as_uint(v);
}
__device__ __forceinline__ float fast_tanh(float x) {
    float a = fabsf(x);
    float e = __expf(a + a);                    // e^{2|x|}; inf -> r = 1
    float r = 1.f - 2.f * __builtin_amdgcn_rcpf(e + 1.f);
    return copysignf(r, x);
}

#define POLL_CHUNK(c, qq)                                                     \
    if (!(done & (1u << c)))                                                  \
        asm volatile("global_load_dwordx4 %0, %1, off offset:" #c "6 sc1"     \
                     : "=v"(qq) : "v"(pp));
// note: offset literal trick: c6 -> 06,16,...  (c in 0..7 gives 6,22,...) — NOT USED.

// Wave-0 poll of the full 1024-word mailbox (read-once per chunk):
// lane l owns words [16l, 16l+16) = rows 16l..16l+15 (8 dwordx4 chunks).
// Re-issues only chunks whose tags haven't matched yet.
__device__ __forceinline__ void poll_wave0(const u64* par_base, unsigned tg,
                                           float* dstLDS, int l, int& budget,
                                           int* s_abort)
{
    const u64* pp = par_base + (size_t)l * 16;
    uv4 q0, q1, q2, q3, q4, q5, q6, q7;
    unsigned done = 0;
    for (;;) {
        if (!(done & 0x01u)) asm volatile("global_load_dwordx4 %0, %1, off sc1"            : "=v"(q0) : "v"(pp));
        if (!(done & 0x02u)) asm volatile("global_load_dwordx4 %0, %1, off offset:16 sc1"  : "=v"(q1) : "v"(pp));
        if (!(done & 0x04u)) asm volatile("global_load_dwordx4 %0, %1, off offset:32 sc1"  : "=v"(q2) : "v"(pp));
        if (!(done & 0x08u)) asm volatile("global_load_dwordx4 %0, %1, off offset:48 sc1"  : "=v"(q3) : "v"(pp));
        if (!(done & 0x10u)) asm volatile("global_load_dwordx4 %0, %1, off offset:64 sc1"  : "=v"(q4) : "v"(pp));
        if (!(done & 0x20u)) asm volatile("global_load_dwordx4 %0, %1, off offset:80 sc1"  : "=v"(q5) : "v"(pp));
        if (!(done & 0x40u)) asm volatile("global_load_dwordx4 %0, %1, off offset:96 sc1"  : "=v"(q6) : "v"(pp));
        if (!(done & 0x80u)) asm volatile("global_load_dwordx4 %0, %1, off offset:112 sc1" : "=v"(q7) : "v"(pp));
        asm volatile("s_waitcnt vmcnt(0)"
                     : "+v"(q0), "+v"(q1), "+v"(q2), "+v"(q3),
                       "+v"(q4), "+v"(q5), "+v"(q6), "+v"(q7));
        done |= ((q0.y == tg) & (q0.w == tg)) ? 0x01u : 0u;
        done |= ((q1.y == tg) & (q1.w == tg)) ? 0x02u : 0u;
        done |= ((q2.y == tg) & (q2.w == tg)) ? 0x04u : 0u;
        done |= ((q3.y == tg) & (q3.w == tg)) ? 0x08u : 0u;
        done |= ((q4.y == tg) & (q4.w == tg)) ? 0x10u : 0u;
        done |= ((q5.y == tg) & (q5.w == tg)) ? 0x20u : 0u;
        done |= ((q6.y == tg) & (q6.w == tg)) ? 0x40u : 0u;
        done |= ((q7.y == tg) & (q7.w == tg)) ? 0x80u : 0u;
        if (done == 0xffu) break;
        if (--budget < 0) { *s_abort = 1; break; }
    }
    // rows 16l..16l+15 -> LDS (values are .x/.z of each chunk)
    float* d = dstLDS + 16 * l;
    vf4 v0 = (vf4){__uint_as_float(q0.x), __uint_as_float(q0.z),
                   __uint_as_float(q1.x), __uint_as_float(q1.z)};
    vf4 v1 = (vf4){__uint_as_float(q2.x), __uint_as_float(q2.z),
                   __uint_as_float(q3.x), __uint_as_float(q3.z)};
    vf4 v2 = (vf4){__uint_as_float(q4.x), __uint_as_float(q4.z),
                   __uint_as_float(q5.x), __uint_as_float(q5.z)};
    vf4 v3 = (vf4){__uint_as_float(q6.x), __uint_as_float(q6.z),
                   __uint_as_float(q7.x), __uint_as_float(q7.z)};
    *(vf4*)&d[0]  = v0;
    *(vf4*)&d[4]  = v1;
    *(vf4*)&d[8]  = v2;
    *(vf4*)&d[12] = v3;
}

// ---------------- Kernel 2: serial recurrence ----------------
// 128 WGs x 512 threads. Wave w (0..7) of WG b owns row r = 8b + w.
// Mailbox: hp[2][1024] tagged u64, word index == row; WG b's 8 rows are one
// contiguous 64B line (full-line dirty, no false sharing across WGs).
// Only wave 0 polls (read-once chunks) and broadcasts h via LDS; waves 1..7
// wait at the step barrier. Dot mapping k = 4l + 256j (conflict-free b128).
__global__ void __launch_bounds__(512, 2) rnn_rec(
    const unsigned short* __restrict__ pre,
    const float* __restrict__ Wi,     // W_h = Wi[:, 1024:2048]
    const float* __restrict__ Wo,
    const float* __restrict__ bo,
    float* __restrict__ out,
    u64* hp)                          // [2][1024] u64, zeroed (tag0|h0=0)
{
    const int tid = threadIdx.x;
    const int w   = tid >> 6;                  // wave 0..7
    const int l   = tid & 63;                  // lane
    const int r   = blockIdx.x * RPW + w;      // this wave's row == mailbox word

    __shared__ __align__(16) float hl[2][HID];
    __shared__ int s_abort;
    if (tid == 0) s_abort = 0;

    // ---- W_h fragment: lane l covers k = 4l + 256j (16 VGPRs, resident) ----
    vf4 wv0, wv1, wv2, wv3;
    {
        const float* wp = Wi + (size_t)r * 2048 + 1024 + 4 * l;
        wv0 = ldg4_pin(wp + 0);
        wv1 = ldg4_pin(wp + 256);
        wv2 = ldg4_pin(wp + 512);
        wv3 = ldg4_pin(wp + 768);
    }
    __syncthreads();                            // covers s_abort init

    int budget = 8000000;                       // hang-proof watchdog

    for (int t = 1; t <= T_STEPS; ++t) {
        const int par = (t - 1) & 1;

        // pre-activation (2B): issue before the poll/barrier to hide latency
        float prev = 0.f;
        if (l == 0) prev = bf2f(pre[(size_t)(t - 1) * HID + r]);

        // ---- wave 0 polls the whole mailbox, stages h_{t-1} into LDS ----
        if (w == 0)
            poll_wave0(hp + (size_t)par * HID, (unsigned)(t - 1),
                       hl[par], l, budget, &s_abort);
        __syncthreads();
        if (s_abort) return;                    // uniform exit (post-barrier)

        // ---- dot(W_h[r], h_{t-1}) : k = 4l + 256j, conflict-free b128 ----
        const float* hb = hl[par];
        vf4 a0 = *(const vf4*)&hb[4 * l + 0];
        vf4 a1 = *(const vf4*)&hb[4 * l + 256];
        vf4 a2 = *(const vf4*)&hb[4 * l + 512];
        vf4 a3 = *(const vf4*)&hb[4 * l + 768];
        float acc0 = 0.f, acc1 = 0.f;
        acc0 = fmaf(wv0.x, a0.x, acc0); acc0 = fmaf(wv0.y, a0.y, acc0);
        acc0 = fmaf(wv0.z, a0.z, acc0); acc0 = fmaf(wv0.w, a0.w, acc0);
        acc1 = fmaf(wv1.x, a1.x, acc1); acc1 = fmaf(wv1.y, a1.y, acc1);
        acc1 = fmaf(wv1.z, a1.z, acc1); acc1 = fmaf(wv1.w, a1.w, acc1);
        acc0 = fmaf(wv2.x, a2.x, acc0); acc0 = fmaf(wv2.y, a2.y, acc0);
        acc0 = fmaf(wv2.z, a2.z, acc0); acc0 = fmaf(wv2.w, a2.w, acc0);
        acc1 = fmaf(wv3.x, a3.x, acc1); acc1 = fmaf(wv3.y, a3.y, acc1);
        acc1 = fmaf(wv3.z, a3.z, acc1); acc1 = fmaf(wv3.w, a3.w, acc1);
        float s = acc0 + acc1;
        s += __shfl_xor(s, 1);
        s += __shfl_xor(s, 2);
        s += __shfl_xor(s, 4);
        s += __shfl_xor(s, 8);
        s += __shfl_xor(s, 16);
        s += __shfl_xor(s, 32);

        if (l == 0) {
            float h = fast_tanh(prev + s);
            __hip_atomic_store(&hp[(size_t)(t & 1) * HID + r],
                               pack_hv(h, (unsigned)t),
                               __ATOMIC_RELAXED, __HIP_MEMORY_SCOPE_AGENT);
        }
    }

    // ---- final projection: out = h_T . W_h2o^T + b_h2o ----
    {
        const int par = T_STEPS & 1;
        if (w == 0)
            poll_wave0(hp + (size_t)par * HID, (unsigned)T_STEPS,
                       hl[0], l, budget, &s_abort);
        __syncthreads();
        if (s_abort) return;

        const float* hb = hl[0];
        const float* wo = Wo + (size_t)r * 1024 + 4 * l;
        vf4 a0 = *(const vf4*)&hb[4 * l + 0];
        vf4 a1 = *(const vf4*)&hb[4 * l + 256];
        vf4 a2 = *(const vf4*)&hb[4 * l + 512];
        vf4 a3 = *(const vf4*)&hb[4 * l + 768];
        vf4 w0 = *(const vf4*)&wo[0];
        vf4 w1 = *(const vf4*)&wo[256];
        vf4 w2 = *(const vf4*)&wo[512];
        vf4 w3 = *(const vf4*)&wo[768];
        float acc0 = 0.f, acc1 = 0.f;
        acc0 = fmaf(w0.x, a0.x, acc0); acc0 = fmaf(w0.y, a0.y, acc0);
        acc0 = fmaf(w0.z, a0.z, acc0); acc0 = fmaf(w0.w, a0.w, acc0);
        acc1 = fmaf(w1.x, a1.x, acc1); acc1 = fmaf(w1.y, a1.y, acc1);
        acc1 = fmaf(w1.z, a1.z, acc1); acc1 = fmaf(w1.w, a1.w, acc1);
        acc0 = fmaf(w2.x, a2.x, acc0); acc0 = fmaf(w2.y, a2.y, acc0);
        acc0 = fmaf(w2.z, a2.z, acc0); acc0 = fmaf(w2.w, a2.w, acc0);
        acc1 = fmaf(w3.x, a3.x, acc1); acc1 = fmaf(w3.y, a3.y, acc1);
        acc1 = fmaf(w3.z, a3.z, acc1); acc1 = fmaf(w3.w, a3.w, acc1);
        float s = acc0 + acc1;
        s += __shfl_xor(s, 1);
        s += __shfl_xor(s, 2);
        s += __shfl_xor(s, 4);
        s += __shfl_xor(s, 8);
        s += __shfl_xor(s, 16);
        s += __shfl_xor(s, 32);
        if (l == 0) out[r] = s + bo[r];
    }
}

extern "C" void kernel_launch(void* const* d_in, const int* in_sizes, int n_in,
                              void* d_out, int out_size, void* d_ws, size_t ws_size,
                              hipStream_t stream) {
    const float* x     = (const float*)d_in[0];   // (1, 32768, 1024)
    const float* W_i2h = (const float*)d_in[1];   // (1024, 2048)
    const float* b_i2h = (const float*)d_in[2];   // (1024,)
    const float* W_h2o = (const float*)d_in[3];   // (1024, 1024)
    const float* b_h2o = (const float*)d_in[4];   // (1024,)
    float* out = (float*)d_out;

    char* base = (char*)d_ws;
    unsigned short* pre = (unsigned short*)base;
    u64* hp = (u64*)(base + PRE_BYTES);

    hipMemsetAsync(hp, 0, HP_BYTES, stream);      // h_0 = 0 with tag 0
    pre_gemm<<<dim3(T_STEPS / BM, HID / BN), 256, 0, stream>>>(x, W_i2h, b_i2h, pre);
    rnn_rec<<<NWG, 512, 0, stream>>>(pre, W_i2h, W_h2o, b_h2o, out, hp);
}